// Round 1
// 1620.397 us; speedup vs baseline: 1.1240x; 1.1240x over previous
//
#include <hip/hip_runtime.h>
#include <cstdint>
#include <cstddef>
#include <math.h>

#define L_ 1024
#define DK_ 64
#define DV_ 64
#define N_ 64
#define H_ 8
#define B_ 8

// readlane broadcast: all lanes get lane `src`'s value of v. src is uniform.
__device__ __forceinline__ float bcast(float v, int src) {
  return __int_as_float(__builtin_amdgcn_readlane(__float_as_int(v), src));
}

// ---------------------------------------------------------------------------
// K1: xm = tril(q_rm @ k^T / 8) written into d_out's attn region.
// (unchanged this round)
// ---------------------------------------------------------------------------
__global__ __launch_bounds__(256) void k1_qk_tril(
    const float* __restrict__ qrm, const float* __restrict__ kk,
    float* __restrict__ xm) {
  const int n  = blockIdx.z;
  const int q0 = blockIdx.y * 64;
  const int j0 = blockIdx.x * 64;
  const int t  = threadIdx.x;

  if (j0 > q0) {  // strictly above diagonal: zeros
    const float4 z = make_float4(0.f, 0.f, 0.f, 0.f);
    #pragma unroll
    for (int i = 0; i < 4; ++i) {
      const int row = (t >> 4) + i * 16;
      const int c4  = t & 15;
      float4* p = (float4*)(xm + ((size_t)(n * L_ + q0 + row)) * L_ + j0);
      p[c4] = z;
    }
    return;
  }

  __shared__ float As[64][65];
  __shared__ float Bs[64][65];
  #pragma unroll
  for (int i = 0; i < 4; ++i) {
    const int row = (t >> 4) + i * 16;
    const int c4  = t & 15;
    const float4 a = ((const float4*)(qrm + ((size_t)(n * L_ + q0 + row)) * DK_))[c4];
    const float4 b = ((const float4*)(kk  + ((size_t)(n * L_ + j0 + row)) * DK_))[c4];
    As[row][c4 * 4 + 0] = a.x; As[row][c4 * 4 + 1] = a.y;
    As[row][c4 * 4 + 2] = a.z; As[row][c4 * 4 + 3] = a.w;
    Bs[row][c4 * 4 + 0] = b.x; Bs[row][c4 * 4 + 1] = b.y;
    Bs[row][c4 * 4 + 2] = b.z; Bs[row][c4 * 4 + 3] = b.w;
  }
  __syncthreads();

  const int ty = t >> 4, tx = t & 15;
  float acc[4][4];
  #pragma unroll
  for (int i = 0; i < 4; ++i)
    #pragma unroll
    for (int j = 0; j < 4; ++j) acc[i][j] = 0.f;

  for (int d = 0; d < 64; ++d) {
    float a[4], b[4];
    #pragma unroll
    for (int i = 0; i < 4; ++i) a[i] = As[ty * 4 + i][d];
    #pragma unroll
    for (int j = 0; j < 4; ++j) b[j] = Bs[tx * 4 + j][d];
    #pragma unroll
    for (int i = 0; i < 4; ++i)
      #pragma unroll
      for (int j = 0; j < 4; ++j) acc[i][j] += a[i] * b[j];
  }

  #pragma unroll
  for (int i = 0; i < 4; ++i) {
    const int gq = q0 + ty * 4 + i;
    float* rowp = xm + ((size_t)(n * L_ + gq)) * L_;
    #pragma unroll
    for (int j = 0; j < 4; ++j) {
      const int gj = j0 + tx * 4 + j;
      rowp[gj] = (gj <= gq) ? acc[i][j] * 0.125f : 0.f;
    }
  }
}

// ---------------------------------------------------------------------------
// K2: xs = relu(conv3x3_{H->H}(xm)) (SAME, zero pad), only where c <= r+4.
// (unchanged this round)
// ---------------------------------------------------------------------------
__global__ __launch_bounds__(256) void k2_conv(
    const float* __restrict__ xm, const float* __restrict__ w,
    float* __restrict__ xs) {
  const int ct = blockIdx.x, rt = blockIdx.y, b = blockIdx.z;
  const int r0 = rt * 4, c0 = ct * 64;
  if (c0 > r0 + 4) return;  // tile entirely outside needed region

  __shared__ float in_s[8][6][68];
  __shared__ float ws[576];
  const int t = threadIdx.x;

  for (int i = t; i < 576; i += 256) ws[i] = w[i];
  for (int e = t; e < 8 * 6 * 66; e += 256) {
    const int hi  = e / 396;
    const int rem = e - hi * 396;
    const int rr  = rem / 66;
    const int cc  = rem - rr * 66;
    const int gr  = r0 - 1 + rr;
    const int gc  = c0 - 1 + cc;
    float v = 0.f;
    if (gr >= 0 && gr < L_ && gc >= 0 && gc < L_)
      v = xm[((size_t)((b * 8 + hi) * L_ + gr)) * L_ + gc];
    in_s[hi][rr][cc] = v;
  }
  __syncthreads();

  const int cc = t & 63;
  const int rr = t >> 6;
  float acc[8];
  #pragma unroll
  for (int ho = 0; ho < 8; ++ho) acc[ho] = 0.f;

  #pragma unroll
  for (int hi = 0; hi < 8; ++hi) {
    float iv[3][3];
    #pragma unroll
    for (int di = 0; di < 3; ++di)
      #pragma unroll
      for (int dj = 0; dj < 3; ++dj)
        iv[di][dj] = in_s[hi][rr + di][cc + dj];
    #pragma unroll
    for (int ho = 0; ho < 8; ++ho) {
      const float* wp = &ws[(ho * 8 + hi) * 9];
      #pragma unroll
      for (int di = 0; di < 3; ++di)
        #pragma unroll
        for (int dj = 0; dj < 3; ++dj)
          acc[ho] += iv[di][dj] * wp[di * 3 + dj];
    }
  }

  const int gr = r0 + rr, gc = c0 + cc;
  #pragma unroll
  for (int ho = 0; ho < 8; ++ho)
    xs[((size_t)((b * 8 + ho) * L_ + gr)) * L_ + gc] = fmaxf(acc[ho], 0.f);
}

// ---------------------------------------------------------------------------
// K3 v2: fused scores + online softmax + attn write + PV.
// Restructured for latency:
//  - XCD-chunked, heavy-first block remap (tail-drain + L2 locality per n)
//  - Phase A: double-buffered k^T LDS tile, next-tile k prefetched into regs
//    under the dot loop; rm/xs/pre gathers prefetched before the dot;
//    ONE barrier per tile (was 2).
//  - Phase C: v tile staged in LDS (double-buffered, prefetched), S re-read
//    prefetched one tile ahead; ONE barrier per tile; no global v in the
//    inner PV loop.
// ---------------------------------------------------------------------------
__global__ __launch_bounds__(256) void k3_fused(
    const float* __restrict__ q, const float* __restrict__ kk,
    const float* __restrict__ v, const float* __restrict__ pre,
    const int* __restrict__ fgp, const float* __restrict__ xs,
    float* attn, float* __restrict__ out) {
  // linear dispatch id -> per-XCD contiguous chunk (8 n's per XCD), and
  // heavy q0 first within each chunk so the tail drains on light blocks.
  const int bid  = blockIdx.y * gridDim.x + blockIdx.x;  // 4096 wgs
  const int work = (bid & 7) * 512 + (bid >> 3);         // bijective, 8 XCDs
  const int n    = work >> 6;
  const int q0   = (63 - (work & 63)) * 16;

  const int t    = threadIdx.x;
  const int lane = t & 63;
  const int g    = t >> 6;  // wave id 0..3
  const int fg   = *fgp;

  const int srow = t >> 4;  // 0..15 (staging row within 16-row stripe)
  const int c4   = t & 15;

  __shared__ float tb[2][64][65];  // A: kt[d][j] transposed; C: vt[c][dv]

  // q held in registers: lane c holds q[n][q0+r_i][c]
  const float* qb = q + ((size_t)(n * L_ + q0)) * DK_;
  float qreg[4];
  #pragma unroll
  for (int i = 0; i < 4; ++i) qreg[i] = qb[(size_t)(g + i * 4) * DK_ + lane];

  float m[4], l[4];
  #pragma unroll
  for (int i = 0; i < 4; ++i) { m[i] = -INFINITY; l[i] = 0.f; }

  int r_[4];
  #pragma unroll
  for (int i = 0; i < 4; ++i) r_[i] = q0 + g + i * 4;

  const int ntiles = (q0 >> 6) + 1;
  const float* kbase = kk + (size_t)n * L_ * DK_;

  // ---------------- Phase A prologue: stage k tile 0 (transposed) ---------
  #pragma unroll
  for (int i = 0; i < 4; ++i) {
    const int row = srow + i * 16;
    const float4 kx = *(const float4*)(kbase + (size_t)row * DK_ + c4 * 4);
    tb[0][c4 * 4 + 0][row] = kx.x;
    tb[0][c4 * 4 + 1][row] = kx.y;
    tb[0][c4 * 4 + 2][row] = kx.z;
    tb[0][c4 * 4 + 3][row] = kx.w;
  }
  __syncthreads();

  // ---------------- Phase A: scores + online (m, l) ----------------
  for (int tile = 0; tile < ntiles; ++tile) {
    const int cur = tile & 1, nxt = cur ^ 1;
    const int j0 = tile * 64;
    const int j  = j0 + lane;
    const bool havenext = (tile + 1) < ntiles;

    // prefetch next k tile into regs (latency hidden under the dot loop)
    float4 kpre[4];
    if (havenext) {
      const float* kb2 = kbase + (size_t)(j0 + 64) * DK_;
      #pragma unroll
      for (int i = 0; i < 4; ++i)
        kpre[i] = *(const float4*)(kb2 + (size_t)(srow + i * 16) * DK_ + c4 * 4);
    }

    // prefetch epilogue operands (coalesced across lanes; predicated on act)
    float rmv[4], prv[4], xsv[4];
    #pragma unroll
    for (int i = 0; i < 4; ++i) {
      const int r = r_[i];
      const bool act = (j <= r);
      rmv[i] = act ? attn[((size_t)(n * L_ + r)) * L_ + j] : 0.f;
      prv[i] = act ? pre[((size_t)(n * L_ + r)) * L_ + j] : 0.f;
      if (fg == 1)
        xsv[i] = (act && r > 0 && j > 0)
                     ? xs[((size_t)(n * L_ + r - 1)) * L_ + (j - 1)] : 0.f;
      else
        xsv[i] = (act && r > 0)
                     ? xs[((size_t)(n * L_ + r - 1)) * L_ + j] : 0.f;
    }

    float dot[4] = {0.f, 0.f, 0.f, 0.f};
    #pragma unroll
    for (int d = 0; d < 64; ++d) {
      const float kd = tb[cur][d][lane];
      #pragma unroll
      for (int i = 0; i < 4; ++i) dot[i] += bcast(qreg[i], d) * kd;
    }

    #pragma unroll
    for (int i = 0; i < 4; ++i) {
      const int r = r_[i];
      float s = -INFINITY;
      if (j <= r) {
        const float sqk = dot[i] * 0.125f;
        const float cnn = (fg == 1)
                              ? ((r == 0 || j == 0) ? rmv[i] : xsv[i])
                              : ((r == 0) ? rmv[i] : xsv[i]);
        const float mixed = cnn * 0.1f + rmv[i] * 0.9f;   // C_MIX
        const float a2    = mixed * 0.4f + sqk * 0.6f;    // B_MIX
        s = prv[i] * 0.1f + a2 * 0.9f;                    // A_MIX
      }
      attn[((size_t)(n * L_ + r)) * L_ + j] = s;  // raw S (or -inf)

      float mt = s;
      #pragma unroll
      for (int o = 32; o > 0; o >>= 1) mt = fmaxf(mt, __shfl_xor(mt, o));
      const float mn = fmaxf(m[i], mt);
      float es = __expf(s - mn);  // s=-inf -> 0
      #pragma unroll
      for (int o = 32; o > 0; o >>= 1) es += __shfl_xor(es, o);
      l[i] = l[i] * __expf(m[i] - mn) + es;
      m[i] = mn;
    }

    // write prefetched k into the other buffer; single barrier per tile
    if (havenext) {
      #pragma unroll
      for (int i = 0; i < 4; ++i) {
        const int row = srow + i * 16;
        tb[nxt][c4 * 4 + 0][row] = kpre[i].x;
        tb[nxt][c4 * 4 + 1][row] = kpre[i].y;
        tb[nxt][c4 * 4 + 2][row] = kpre[i].z;
        tb[nxt][c4 * 4 + 3][row] = kpre[i].w;
      }
    }
    __syncthreads();
  }

  // ---------------- Phase C: normalize + attn write + PV ----------------
  float invl[4];
  #pragma unroll
  for (int i = 0; i < 4; ++i) invl[i] = 1.f / l[i];

  float acc[4] = {0.f, 0.f, 0.f, 0.f};
  const float* vb = v + (size_t)n * L_ * DV_;

  // prologue: stage v tile 0 (straight copy) + load S tile 0
  #pragma unroll
  for (int i = 0; i < 4; ++i) {
    const int row = srow + i * 16;
    const float4 vx = *(const float4*)(vb + (size_t)row * DV_ + c4 * 4);
    tb[0][row][c4 * 4 + 0] = vx.x;
    tb[0][row][c4 * 4 + 1] = vx.y;
    tb[0][row][c4 * 4 + 2] = vx.z;
    tb[0][row][c4 * 4 + 3] = vx.w;
  }
  float s_cur[4];
  #pragma unroll
  for (int i = 0; i < 4; ++i)
    s_cur[i] = attn[((size_t)(n * L_ + r_[i])) * L_ + lane];
  __syncthreads();  // also drains Phase A raw-S stores (barrier semantics)

  for (int tile = 0; tile < ntiles; ++tile) {
    const int cur = tile & 1, nxt = cur ^ 1;
    const int j0 = tile * 64;
    const int j  = j0 + lane;
    const bool havenext = (tile + 1) < ntiles;

    // prefetch next v tile + next S stripe (hidden under PV loop)
    float4 vpre[4];
    float s_nxt[4];
    if (havenext) {
      const float* vb2 = vb + (size_t)(j0 + 64) * DV_;
      #pragma unroll
      for (int i = 0; i < 4; ++i)
        vpre[i] = *(const float4*)(vb2 + (size_t)(srow + i * 16) * DV_ + c4 * 4);
      #pragma unroll
      for (int i = 0; i < 4; ++i)
        s_nxt[i] = attn[((size_t)(n * L_ + r_[i])) * L_ + j + 64];
    }

    float p[4];
    #pragma unroll
    for (int i = 0; i < 4; ++i) {
      p[i] = __expf(s_cur[i] - m[i]) * invl[i];  // -inf -> 0
      attn[((size_t)(n * L_ + r_[i])) * L_ + j] = p[i];
    }

    #pragma unroll
    for (int c = 0; c < 64; ++c) {
      const float vv = tb[cur][c][lane];
      #pragma unroll
      for (int i = 0; i < 4; ++i) acc[i] += bcast(p[i], c) * vv;
    }

    if (havenext) {
      #pragma unroll
      for (int i = 0; i < 4; ++i) {
        const int row = srow + i * 16;
        tb[nxt][row][c4 * 4 + 0] = vpre[i].x;
        tb[nxt][row][c4 * 4 + 1] = vpre[i].y;
        tb[nxt][row][c4 * 4 + 2] = vpre[i].z;
        tb[nxt][row][c4 * 4 + 3] = vpre[i].w;
      }
      #pragma unroll
      for (int i = 0; i < 4; ++i) s_cur[i] = s_nxt[i];
    }
    __syncthreads();
  }

  #pragma unroll
  for (int i = 0; i < 4; ++i)
    out[((size_t)(n * L_ + r_[i])) * DV_ + lane] = acc[i];
}

// ---------------------------------------------------------------------------
extern "C" void kernel_launch(void* const* d_in, const int* in_sizes, int n_in,
                              void* d_out, int out_size, void* d_ws,
                              size_t ws_size, hipStream_t stream) {
  const float* q   = (const float*)d_in[0];
  const float* kk  = (const float*)d_in[1];
  const float* v   = (const float*)d_in[2];
  const float* qrm = (const float*)d_in[3];
  const float* pre = (const float*)d_in[4];
  const float* cw  = (const float*)d_in[5];
  // d_in[6] = mask (deterministic causal, computed analytically)
  const int* fg = (const int*)d_in[7];

  float* out  = (float*)d_out;
  float* attn = out + (size_t)N_ * L_ * DV_;  // second output; also rm/S staging
  float* xs   = (float*)d_ws;                 // conv output, N*L*L f32

  k1_qk_tril<<<dim3(16, 16, 64), 256, 0, stream>>>(qrm, kk, attn);
  k2_conv<<<dim3(16, 256, 8), 256, 0, stream>>>(attn, cw, xs);
  k3_fused<<<dim3(64, 64), 256, 0, stream>>>(q, kk, v, pre, fg, xs, attn, out);
}